// Round 1
// baseline (675.608 us; speedup 1.0000x reference)
//
#include <hip/hip_runtime.h>
#include <stdint.h>

// out[8192,4096] = x[8192,4096] @ (A[4096,16] @ B[16,4096]), ALL FP32.
// Fused low-rank. v2: anti-spill + occupancy fix.
//   - RPW 4->2 (acc = 32 VGPRs), no local float[16] arrays (spill bait),
//     explicit float4 components everywhere. Peak live set ~90 VGPR < 128.
//   - MB 16->8 -> grid 1024 blocks = 4 blocks/CU = 16 waves/CU (4/SIMD max
//     at the 128-VGPR cap from __launch_bounds__(256,4)).
// Ideal HBM traffic ~268 MB -> ~43 us floor at 6.3 TB/s achievable.

#define KD 4096   // D_IN
#define ND 4096   // D_OUT
#define NR 16     // rank
#define BLK 256
#define RPW 2     // rows per wave
#define MB 8      // rows per block = 4 waves * RPW

// acc[r] += xf * A_row[r], A row held as 4 float4s (a0..a3)
#define FMA16(ACC, XF)                                        \
    ACC[0]  = fmaf((XF), a0.x, ACC[0]);                       \
    ACC[1]  = fmaf((XF), a0.y, ACC[1]);                       \
    ACC[2]  = fmaf((XF), a0.z, ACC[2]);                       \
    ACC[3]  = fmaf((XF), a0.w, ACC[3]);                       \
    ACC[4]  = fmaf((XF), a1.x, ACC[4]);                       \
    ACC[5]  = fmaf((XF), a1.y, ACC[5]);                       \
    ACC[6]  = fmaf((XF), a1.z, ACC[6]);                       \
    ACC[7]  = fmaf((XF), a1.w, ACC[7]);                       \
    ACC[8]  = fmaf((XF), a2.x, ACC[8]);                       \
    ACC[9]  = fmaf((XF), a2.y, ACC[9]);                       \
    ACC[10] = fmaf((XF), a2.z, ACC[10]);                      \
    ACC[11] = fmaf((XF), a2.w, ACC[11]);                      \
    ACC[12] = fmaf((XF), a3.x, ACC[12]);                      \
    ACC[13] = fmaf((XF), a3.y, ACC[13]);                      \
    ACC[14] = fmaf((XF), a3.z, ACC[14]);                      \
    ACC[15] = fmaf((XF), a3.w, ACC[15]);

__device__ __forceinline__ float f4c(const float4& v, int j) {
    // j is always a compile-time constant after unrolling
    return j == 0 ? v.x : j == 1 ? v.y : j == 2 ? v.z : v.w;
}

__global__ __launch_bounds__(BLK, 4)
void lora_fused(const float* __restrict__ X,
                const float* __restrict__ A,
                const float* __restrict__ Bm,
                float* __restrict__ O)
{
    __shared__ float t_s[MB][NR];

    const int tid  = threadIdx.x;
    const int wv   = tid >> 6;
    const int lane = tid & 63;
    const size_t m0 = (size_t)blockIdx.x * MB;
    const int row0 = wv * RPW;

    // ---------------- Phase A: T = X @ A ----------------
    float acc0[NR], acc1[NR];
    #pragma unroll
    for (int r = 0; r < NR; ++r) { acc0[r] = 0.f; acc1[r] = 0.f; }

    const float* xp0 = X + (m0 + row0) * (size_t)KD;
    const float* xp1 = xp0 + KD;

    #pragma unroll 1
    for (int s = 0; s < KD / 256; ++s) {         // 16 steps; lane owns 4 consecutive k
        const int k0 = s * 256 + lane * 4;
        const float4 x0 = *reinterpret_cast<const float4*>(xp0 + k0);
        const float4 x1 = *reinterpret_cast<const float4*>(xp1 + k0);

        #pragma unroll
        for (int j = 0; j < 4; ++j) {
            const float* ap = A + (size_t)(k0 + j) * NR;
            const float4 a0 = *reinterpret_cast<const float4*>(ap + 0);
            const float4 a1 = *reinterpret_cast<const float4*>(ap + 4);
            const float4 a2 = *reinterpret_cast<const float4*>(ap + 8);
            const float4 a3 = *reinterpret_cast<const float4*>(ap + 12);
            const float xf0 = f4c(x0, j);
            const float xf1 = f4c(x1, j);
            FMA16(acc0, xf0)
            FMA16(acc1, xf1)
        }
    }

    // Butterfly reduce across the 64-lane wave
    #pragma unroll
    for (int off = 32; off > 0; off >>= 1) {
        #pragma unroll
        for (int r = 0; r < NR; ++r) {
            acc0[r] += __shfl_xor(acc0[r], off, 64);
            acc1[r] += __shfl_xor(acc1[r], off, 64);
        }
    }

    if (lane == 0) {
        #pragma unroll
        for (int r = 0; r < NR; ++r) {
            t_s[row0 + 0][r] = acc0[r];
            t_s[row0 + 1][r] = acc1[r];
        }
    }
    __syncthreads();

    // ---------------- Phase B: O = T @ B ----------------
    #pragma unroll 1
    for (int p = 0; p < ND / (BLK * 4); ++p) {   // 4 passes, 4 cols/thread
        const int j0 = p * (BLK * 4) + tid * 4;

        float4 b[NR];
        #pragma unroll
        for (int r = 0; r < NR; ++r)
            b[r] = *reinterpret_cast<const float4*>(Bm + (size_t)r * ND + j0);

        #pragma unroll
        for (int m = 0; m < MB; ++m) {
            // broadcast LDS reads, ds_read_b128 x4
            const float4 t0 = *reinterpret_cast<const float4*>(&t_s[m][0]);
            const float4 t1 = *reinterpret_cast<const float4*>(&t_s[m][4]);
            const float4 t2 = *reinterpret_cast<const float4*>(&t_s[m][8]);
            const float4 t3 = *reinterpret_cast<const float4*>(&t_s[m][12]);

            float o0 = 0.f, o1 = 0.f, o2 = 0.f, o3 = 0.f;
            #pragma unroll
            for (int rq = 0; rq < 4; ++rq) {
                const float4 tq = rq == 0 ? t0 : rq == 1 ? t1 : rq == 2 ? t2 : t3;
                #pragma unroll
                for (int j = 0; j < 4; ++j) {
                    const float tv = f4c(tq, j);
                    const int r = rq * 4 + j;
                    o0 = fmaf(tv, b[r].x, o0);
                    o1 = fmaf(tv, b[r].y, o1);
                    o2 = fmaf(tv, b[r].z, o2);
                    o3 = fmaf(tv, b[r].w, o3);
                }
            }
            *reinterpret_cast<float4*>(O + (m0 + m) * (size_t)ND + j0) =
                make_float4(o0, o1, o2, o3);
        }
    }
}

extern "C" void kernel_launch(void* const* d_in, const int* in_sizes, int n_in,
                              void* d_out, int out_size, void* d_ws, size_t ws_size,
                              hipStream_t stream) {
    const float* X  = (const float*)d_in[0];   // [4,2048,4096] fp32
    const float* A  = (const float*)d_in[1];   // [4096,16]     fp32
    const float* Bm = (const float*)d_in[2];   // [16,4096]     fp32
    float* O = (float*)d_out;                  // [4,2048,4096] fp32
    lora_fused<<<8192 / MB, BLK, 0, stream>>>(X, A, Bm, O);
}